// Round 1
// baseline (41.243 us; speedup 1.0000x reference)
//
#include <hip/hip_runtime.h>

// PatchStd: out = sqrt( boxconv7(x^2) - boxconv7(x)^2 ), uniform 7x7 weight w.
// x: [16, 1, 1024, 1024] fp32, zero padding 3 on each side.
//
// Strategy: uniform weight => conv = w * (windowed sum). Separable sliding
// sums: each thread owns 4 adjacent output columns and a 16-row vertical
// strip. Per input row: 3 aligned float4 loads (cols c0-4 .. c0+7), build
// horizontal 7-sums of x and x^2 for the 4 columns by sliding-window, push
// into a 7-deep register ring (static indices via 7-phase unroll), and emit
// one output row by re-summing the ring vertically. No LDS, no barriers.

#define IMG_W 1024
#define IMG_H 1024
#define SH    16            // output rows per block (strip height)

__global__ __launch_bounds__(256) void patchstd_kernel(
    const float* __restrict__ img, const float* __restrict__ wptr,
    float* __restrict__ out)
{
    const int tx = threadIdx.x;
    const int c0 = tx << 2;                       // first of 4 output cols
    const int y0 = blockIdx.y * SH;               // first output row of strip
    const float* base  = img + (size_t)blockIdx.z * (IMG_W * IMG_H);
    float*       obase = out + (size_t)blockIdx.z * (IMG_W * IMG_H);
    const float w = wptr[0];

    const bool interior = (tx > 0) && (tx < 255); // all 12 cols in-range

    float rh[7][4];   // ring: horizontal sums of x
    float rq[7][4];   // ring: horizontal sums of x^2

    // Compute h (7-tap sum of x) and q (7-tap sum of x^2) for this thread's
    // 4 output columns on input row `row`; zero rows outside the image.
    auto load_row = [&](int row, float* h, float* q) {
        float v[12];
        if (row >= 0 && row < IMG_H) {
            const float* rp = base + row * IMG_W;
            if (interior) {
                float4 a = *reinterpret_cast<const float4*>(rp + c0 - 4);
                float4 b = *reinterpret_cast<const float4*>(rp + c0);
                float4 c = *reinterpret_cast<const float4*>(rp + c0 + 4);
                v[0]=a.x; v[1]=a.y; v[2]=a.z;  v[3]=a.w;
                v[4]=b.x; v[5]=b.y; v[6]=b.z;  v[7]=b.w;
                v[8]=c.x; v[9]=c.y; v[10]=c.z; v[11]=c.w;
            } else {
                #pragma unroll
                for (int i = 0; i < 12; ++i) {
                    int col = c0 - 4 + i;
                    v[i] = (col >= 0 && col < IMG_W) ? rp[col] : 0.f;
                }
            }
        } else {
            #pragma unroll
            for (int i = 0; i < 12; ++i) v[i] = 0.f;
        }
        // window for output col (c0+k) = v[k+1 .. k+7]
        float s = v[1]+v[2]+v[3]+v[4]+v[5]+v[6]+v[7];
        h[0] = s;
        s = s - v[1] + v[8];  h[1] = s;
        s = s - v[2] + v[9];  h[2] = s;
        h[3] = s - v[3] + v[10];
        float sq[11];
        #pragma unroll
        for (int i = 1; i <= 10; ++i) sq[i] = v[i] * v[i];
        float t = sq[1]+sq[2]+sq[3]+sq[4]+sq[5]+sq[6]+sq[7];
        q[0] = t;
        t = t - sq[1] + sq[8];  q[1] = t;
        t = t - sq[2] + sq[9];  q[2] = t;
        q[3] = t - sq[3] + sq[10];
    };

    // Prologue: input rows y0-3 .. y0+2 into ring slots 0..5.
    #pragma unroll
    for (int j = 0; j < 6; ++j)
        load_row(y0 - 3 + j, rh[j], rq[j]);

    // Main loop: 7-phase unrolled so the ring slot index is compile-time.
    for (int g = 0; g < (SH + 6) / 7; ++g) {
        #pragma unroll
        for (int p = 0; p < 7; ++p) {
            const int rr = g * 7 + p;
            if (rr >= SH) break;
            const int slot = (6 + p) % 7;         // static after unroll
            load_row(y0 + rr + 3, rh[slot], rq[slot]);

            float o[4];
            #pragma unroll
            for (int k = 0; k < 4; ++k) {
                float s1 = rh[0][k]+rh[1][k]+rh[2][k]+rh[3][k]+rh[4][k]+rh[5][k]+rh[6][k];
                float s2 = rq[0][k]+rq[1][k]+rq[2][k]+rq[3][k]+rq[4][k]+rq[5][k]+rq[6][k];
                float mean = w * s1;
                float var  = fmaf(w, s2, -(mean * mean));
                o[k] = sqrtf(fmaxf(var, 0.f));
            }
            *reinterpret_cast<float4*>(obase + (size_t)(y0 + rr) * IMG_W + c0) =
                make_float4(o[0], o[1], o[2], o[3]);
        }
    }
}

extern "C" void kernel_launch(void* const* d_in, const int* in_sizes, int n_in,
                              void* d_out, int out_size, void* d_ws, size_t ws_size,
                              hipStream_t stream) {
    const float* img = (const float*)d_in[0];
    const float* wt  = (const float*)d_in[1];
    float* out = (float*)d_out;
    const int batch = in_sizes[0] / (IMG_W * IMG_H);   // 16
    dim3 grid(1, IMG_H / SH, batch);
    patchstd_kernel<<<grid, dim3(256, 1, 1), 0, stream>>>(img, wt, out);
}

// Round 2
// 36.164 us; speedup vs baseline: 1.1405x; 1.1405x over previous
//
#include <hip/hip_runtime.h>

// PatchStd: out = sqrt( boxconv7(x^2) - boxconv7(x)^2 ), uniform 7x7 weight w.
// x: [16, 1, 1024, 1024] fp32, zero padding 3 on each side.
//
// Uniform weight => conv = w * windowed sum. Each thread owns 4 adjacent
// output columns and an 8-row vertical strip (SH=8: 2048 blocks = 8/CU for
// latency hiding; round-1 showed 16-row strips left occupancy at 23%).
// Per input row: 3 aligned float4 loads, sliding-window horizontal 7-sums of
// x and x^2 into a 7-deep register ring (static indices via 7-phase unroll),
// then vertical 7-sum per output row. Raw loads are software-pipelined one
// row ahead to double memory-level parallelism. No LDS, no barriers.

#define IMG_W 1024
#define IMG_H 1024
#define SH    8             // output rows per block (strip height)

__global__ __launch_bounds__(256) void patchstd_kernel(
    const float* __restrict__ img, const float* __restrict__ wptr,
    float* __restrict__ out)
{
    const int tx = threadIdx.x;
    const int c0 = tx << 2;                       // first of 4 output cols
    const int y0 = blockIdx.y * SH;               // first output row of strip
    const float* base  = img + (size_t)blockIdx.z * (IMG_W * IMG_H);
    float*       obase = out + (size_t)blockIdx.z * (IMG_W * IMG_H);
    const float w = wptr[0];

    const bool interior = (tx > 0) && (tx < 255); // all 12 cols in-range

    float rh[7][4];   // ring: horizontal sums of x
    float rq[7][4];   // ring: horizontal sums of x^2

    // Load 12 raw pixels (cols c0-4 .. c0+7) of input row `row`; zeros outside.
    auto load_raw = [&](int row, float* v) {
        if (row >= 0 && row < IMG_H) {
            const float* rp = base + row * IMG_W;
            if (interior) {
                float4 a = *reinterpret_cast<const float4*>(rp + c0 - 4);
                float4 b = *reinterpret_cast<const float4*>(rp + c0);
                float4 c = *reinterpret_cast<const float4*>(rp + c0 + 4);
                v[0]=a.x; v[1]=a.y; v[2]=a.z;  v[3]=a.w;
                v[4]=b.x; v[5]=b.y; v[6]=b.z;  v[7]=b.w;
                v[8]=c.x; v[9]=c.y; v[10]=c.z; v[11]=c.w;
            } else {
                #pragma unroll
                for (int i = 0; i < 12; ++i) {
                    int col = c0 - 4 + i;
                    v[i] = (col >= 0 && col < IMG_W) ? rp[col] : 0.f;
                }
            }
        } else {
            #pragma unroll
            for (int i = 0; i < 12; ++i) v[i] = 0.f;
        }
    };

    // Horizontal 7-sums for the 4 output columns from 12 raw values.
    // window for output col (c0+k) = v[k+1 .. k+7]
    auto hsum = [&](const float* v, float* h, float* q) {
        float s = v[1]+v[2]+v[3]+v[4]+v[5]+v[6]+v[7];
        h[0] = s;
        s = s - v[1] + v[8];  h[1] = s;
        s = s - v[2] + v[9];  h[2] = s;
        h[3] = s - v[3] + v[10];
        float sq[11];
        #pragma unroll
        for (int i = 1; i <= 10; ++i) sq[i] = v[i] * v[i];
        float t = sq[1]+sq[2]+sq[3]+sq[4]+sq[5]+sq[6]+sq[7];
        q[0] = t;
        t = t - sq[1] + sq[8];  q[1] = t;
        t = t - sq[2] + sq[9];  q[2] = t;
        q[3] = t - sq[3] + sq[10];
    };

    // Prologue: raw rows y0-3 .. y0+2 into ring slots 0..5, plus the first
    // main-loop row (y0+3) prefetched into cur_v.
    {
        float v0[12], v1[12], v2[12], v3[12], v4[12], v5[12];
        load_raw(y0 - 3, v0); load_raw(y0 - 2, v1); load_raw(y0 - 1, v2);
        load_raw(y0 + 0, v3); load_raw(y0 + 1, v4); load_raw(y0 + 2, v5);
        hsum(v0, rh[0], rq[0]); hsum(v1, rh[1], rq[1]); hsum(v2, rh[2], rq[2]);
        hsum(v3, rh[3], rq[3]); hsum(v4, rh[4], rq[4]); hsum(v5, rh[5], rq[5]);
    }
    float curv[12], nxtv[12];
    load_raw(y0 + 3, curv);

    // Main loop: 7-phase unrolled so ring slot indices are compile-time.
    #pragma unroll
    for (int rr = 0; rr < SH; ++rr) {
        const int slot = (6 + rr) % 7;            // static after unroll
        // Prefetch next row's raw data before consuming curv.
        load_raw(y0 + rr + 4, nxtv);
        hsum(curv, rh[slot], rq[slot]);

        float o[4];
        #pragma unroll
        for (int k = 0; k < 4; ++k) {
            float s1 = rh[0][k]+rh[1][k]+rh[2][k]+rh[3][k]+rh[4][k]+rh[5][k]+rh[6][k];
            float s2 = rq[0][k]+rq[1][k]+rq[2][k]+rq[3][k]+rq[4][k]+rq[5][k]+rq[6][k];
            float mean = w * s1;
            float var  = fmaf(w, s2, -(mean * mean));
            o[k] = sqrtf(fmaxf(var, 0.f));
        }
        *reinterpret_cast<float4*>(obase + (size_t)(y0 + rr) * IMG_W + c0) =
            make_float4(o[0], o[1], o[2], o[3]);

        #pragma unroll
        for (int i = 0; i < 12; ++i) curv[i] = nxtv[i];
    }
}

extern "C" void kernel_launch(void* const* d_in, const int* in_sizes, int n_in,
                              void* d_out, int out_size, void* d_ws, size_t ws_size,
                              hipStream_t stream) {
    const float* img = (const float*)d_in[0];
    const float* wt  = (const float*)d_in[1];
    float* out = (float*)d_out;
    const int batch = in_sizes[0] / (IMG_W * IMG_H);   // 16
    dim3 grid(1, IMG_H / SH, batch);
    patchstd_kernel<<<grid, dim3(256, 1, 1), 0, stream>>>(img, wt, out);
}